// Round 7
// baseline (59.157 us; speedup 1.0000x reference)
//
#include <hip/hip_runtime.h>

// ParticleI2cCell: pairwise Gaussian loglik (P x P, D=4) + two row-LSEs.
// smoothed[i] = log(sum_j e_ij*exp(w_j)) - log(sum_j e_ij*exp(lw_j))
// e_ij = exp(m_i . s_j - ||s_j||^2/2)   [exp(-||m_i||^2/2) cancels in the
// log-ratio and is dropped].
//
// R6 synthesis: all prior structures pinned VALUBusy at 23-29%.
//  - R6 (scalar s_load j-walk): scalar-cache path can't feed 32 waves/CU.
//  - R2 (LDS broadcast): right feed path, but only 512 blocks + slow reduce.
//  - R4 (2048 blocks): right occupancy, but 32/256-thread staging + a
//    128-block latency-bound reduce.
// This round: rows-on-lanes R=4, NJ=256 -> 2048 blocks (8/CU, 32 waves/CU),
// full-thread LDS staging of the 32-entry j-slice (broadcast ds_read_b128 in
// the hot loop), and a fully-parallel 2048-block butterfly reduce.

constexpr float LOG2E = 1.4426950408889634f;
constexpr float LN2   = 0.6931471805599453f;

// ---------------- precompute: j-table [P][8] AoS + means SoA [4][P] --------
__global__ __launch_bounds__(256) void precompute_k(
    const float* __restrict__ particles,
    const float* __restrict__ samples,
    const float* __restrict__ weights,
    const float* __restrict__ log_weights,
    const float* __restrict__ A,
    const float* __restrict__ B,
    const float* __restrict__ log_sigma,
    float* __restrict__ jdata,   // [P][8]: {LOG2E*s0..s3, K*||s||^2, e^lw, e^w, 0}
    float* __restrict__ msoa,    // [4][P] scaled means
    int P)
{
    int i = blockIdx.x * blockDim.x + threadIdx.x;
    if (i >= P) return;

    const float K = -0.5f * LOG2E;

    float inv_s[4];
#pragma unroll
    for (int k = 0; k < 4; ++k)
        inv_s[k] = __builtin_amdgcn_exp2f(-log_sigma[k] * LOG2E);

    float4 sv = reinterpret_cast<const float4*>(samples)[i];
    float s0 = sv.x * inv_s[0], s1 = sv.y * inv_s[1];
    float s2 = sv.z * inv_s[2], s3 = sv.w * inv_s[3];
    float sn = s0*s0 + s1*s1 + s2*s2 + s3*s3;

    float4* jd = reinterpret_cast<float4*>(jdata + (size_t)i * 8);
    jd[0] = make_float4(LOG2E*s0, LOG2E*s1, LOG2E*s2, LOG2E*s3);
    jd[1] = make_float4(K * sn,
                        __builtin_amdgcn_exp2f(log_weights[i] * LOG2E),
                        __builtin_amdgcn_exp2f(weights[i] * LOG2E),
                        0.f);

    const float2* p2 = reinterpret_cast<const float2*>(particles) + (size_t)i * 3;
    float2 x01 = p2[0], x23 = p2[1], u01 = p2[2];
    float x[4] = {x01.x, x01.y, x23.x, x23.y};
    float u[2] = {u01.x, u01.y};
#pragma unroll
    for (int k = 0; k < 4; ++k) {
        float mean =       A[k*4+0] * x[0];
        mean = fmaf(A[k*4+1], x[1], mean);
        mean = fmaf(A[k*4+2], x[2], mean);
        mean = fmaf(A[k*4+3], x[3], mean);
        mean = fmaf(B[k*2+0], u[0], mean);
        mean = fmaf(B[k*2+1], u[1], mean);
        msoa[(size_t)k * P + i] = mean * inv_s[k];
    }
}

// ---------------- pair kernel ----------------------------------------------
// grid = (NJ, P/(R*BLOCK)) = (256, 8) = 2048 blocks. Each block: stage its
// JCHUNK=32-entry j-slice (1KB) into LDS with all threads, then R=4 rows per
// thread over the slice. LDS reads are wave-broadcast (conflict-free).
template <int R, int BLOCK, int JCHUNK>
__global__ __launch_bounds__(BLOCK, 8) void pair_k(
    const float* __restrict__ jdata,   // [P][8]
    const float* __restrict__ msoa,    // [4][P]
    float* __restrict__ part1,         // [NJ][P]
    float* __restrict__ part2,         // [NJ][P]
    int P)
{
    const int tid = threadIdx.x;
    const int jc  = blockIdx.x;
    const int rowBase = blockIdx.y * (BLOCK * R);

    __shared__ __align__(16) float jds[JCHUNK * 8];

    // full-thread staging: one float per thread (JCHUNK*8 == BLOCK)
    static_assert(JCHUNK * 8 == BLOCK, "staging assumes 1 float/thread");
    jds[tid] = jdata[(size_t)jc * JCHUNK * 8 + tid];

    float m0[R], m1[R], m2[R], m3[R], a1[R], a2[R];
#pragma unroll
    for (int r = 0; r < R; ++r) {
        int row = rowBase + tid + r * BLOCK;
        m0[r] = msoa[0 * (size_t)P + row];
        m1[r] = msoa[1 * (size_t)P + row];
        m2[r] = msoa[2 * (size_t)P + row];
        m3[r] = msoa[3 * (size_t)P + row];
        a1[r] = 0.f;
        a2[r] = 0.f;
    }

    __syncthreads();

    const float4* jf = reinterpret_cast<const float4*>(jds);
#pragma unroll 8
    for (int jj = 0; jj < JCHUNK; ++jj) {
        float4 av = jf[2 * jj];        // broadcast ds_read_b128
        float4 bv = jf[2 * jj + 1];
#pragma unroll
        for (int r = 0; r < R; ++r) {
            float t = fmaf(m0[r], av.x, bv.x);
            t = fmaf(m1[r], av.y, t);
            t = fmaf(m2[r], av.z, t);
            t = fmaf(m3[r], av.w, t);
            float e = __builtin_amdgcn_exp2f(t);
            a1[r] = fmaf(e, bv.y, a1[r]);
            a2[r] = fmaf(e, bv.z, a2[r]);
        }
    }

#pragma unroll
    for (int r = 0; r < R; ++r) {
        int row = rowBase + tid + r * BLOCK;
        part1[(size_t)jc * P + row] = a1[r];   // coalesced
        part2[(size_t)jc * P + row] = a2[r];
    }
}

// ---------------- reduce: one 64-lane group per row ------------------------
// lane covers slices {lane, lane+64, lane+128, lane+192}; butterfly; fixed
// order -> deterministic. grid = P/4 = 2048 blocks.
template <int NJ>
__global__ __launch_bounds__(256) void reduce_k(
    const float* __restrict__ part1,
    const float* __restrict__ part2,
    float* __restrict__ out, int P)
{
    const int lane = threadIdx.x & 63;
    const int grp  = threadIdx.x >> 6;          // 0..3
    const int row  = blockIdx.x * 4 + grp;

    float s1 = 0.f, s2 = 0.f;
#pragma unroll
    for (int q = 0; q < NJ / 64; ++q) {
        int sl = lane + q * 64;
        s1 += part1[(size_t)sl * P + row];
        s2 += part2[(size_t)sl * P + row];
    }
#pragma unroll
    for (int mask = 32; mask >= 1; mask >>= 1) {
        s1 += __shfl_xor(s1, mask, 64);
        s2 += __shfl_xor(s2, mask, 64);
    }
    if (lane == 0)
        out[row] = (__builtin_amdgcn_logf(s2) - __builtin_amdgcn_logf(s1)) * LN2;
}

extern "C" void kernel_launch(void* const* d_in, const int* in_sizes, int n_in,
                              void* d_out, int out_size, void* d_ws, size_t ws_size,
                              hipStream_t stream)
{
    const float* particles   = (const float*)d_in[0];
    const float* samples     = (const float*)d_in[1];
    const float* weights     = (const float*)d_in[2];
    const float* log_weights = (const float*)d_in[3];
    const float* A           = (const float*)d_in[4];
    const float* B           = (const float*)d_in[5];
    const float* log_sigma   = (const float*)d_in[6];

    const int P = in_sizes[2];  // weights is (P,)

    constexpr int BLOCK = 256, R = 4, JCHUNK = 32;
    constexpr int NJ_MAX = 256;
    const int NJ = P / JCHUNK;                  // 256 at P=8192

    // ws layout: jdata P*8 | msoa 4*P | part1 NJ*P | part2 NJ*P (~16.9MB)
    float* jdata = (float*)d_ws;
    float* msoa  = jdata + (size_t)P * 8;
    float* part1 = msoa + (size_t)P * 4;
    float* part2 = part1 + (size_t)NJ * P;

    precompute_k<<<(P + BLOCK - 1) / BLOCK, BLOCK, 0, stream>>>(
        particles, samples, weights, log_weights, A, B, log_sigma,
        jdata, msoa, P);

    dim3 grid(NJ, P / (R * BLOCK));             // (256, 8) = 2048 blocks
    pair_k<R, BLOCK, JCHUNK><<<grid, BLOCK, 0, stream>>>(
        jdata, msoa, part1, part2, P);

    if (NJ == NJ_MAX) {
        reduce_k<NJ_MAX><<<P / 4, 256, 0, stream>>>(part1, part2, (float*)d_out, P);
    } else if (NJ == 128) {
        reduce_k<128><<<P / 4, 256, 0, stream>>>(part1, part2, (float*)d_out, P);
    } else {
        reduce_k<64><<<P / 4, 256, 0, stream>>>(part1, part2, (float*)d_out, P);
    }
}

// Round 8
// 27.040 us; speedup vs baseline: 2.1878x; 2.1878x over previous
//
#include <hip/hip_runtime.h>

// ParticleI2cCell: pairwise Gaussian loglik (P x P, D=4) + two row-LSEs.
// smoothed[i] = log(sum_j e_ij*exp(w_j)) - log(sum_j e_ij*exp(lw_j))
// e_ij = exp(m_i . s_j - ||s_j||^2/2)   [exp(-||m_i||^2/2) cancels in the
// log-ratio and is dropped].
//
// R7 lesson: the partials-over-j architecture always loses — one side of the
// round-trip is strided (R7 reduce: lane-stride P => 64 lines/wave-load) or
// the reduce is latency-bound (R1/R2). This version removes partials AND the
// second kernel: j is split WITHIN a block (thread t sweeps j = t + 256*it),
// rows (TR=8) are block-uniform SGPR means, accumulators are reduced by an
// in-register 64-lane butterfly + one small LDS cross-wave combine.
// Hot path: per-lane coalesced vector loads (VMEM/L1, not scalar cache, not
// LDS), zero barriers, 1024 blocks (4/CU).

constexpr float LOG2E = 1.4426950408889634f;
constexpr float LN2   = 0.6931471805599453f;

// ---------------- precompute: j-table [P][8] AoS + means SoA [4][P] --------
__global__ __launch_bounds__(256) void precompute_k(
    const float* __restrict__ particles,
    const float* __restrict__ samples,
    const float* __restrict__ weights,
    const float* __restrict__ log_weights,
    const float* __restrict__ A,
    const float* __restrict__ B,
    const float* __restrict__ log_sigma,
    float* __restrict__ jdata,   // [P][8]: {LOG2E*s0..s3, K*||s||^2, e^lw, e^w, 0}
    float* __restrict__ msoa,    // [4][P] scaled means
    int P)
{
    int i = blockIdx.x * blockDim.x + threadIdx.x;
    if (i >= P) return;

    const float K = -0.5f * LOG2E;

    float inv_s[4];
#pragma unroll
    for (int k = 0; k < 4; ++k)
        inv_s[k] = __builtin_amdgcn_exp2f(-log_sigma[k] * LOG2E);

    float4 sv = reinterpret_cast<const float4*>(samples)[i];
    float s0 = sv.x * inv_s[0], s1 = sv.y * inv_s[1];
    float s2 = sv.z * inv_s[2], s3 = sv.w * inv_s[3];
    float sn = s0*s0 + s1*s1 + s2*s2 + s3*s3;

    float4* jd = reinterpret_cast<float4*>(jdata + (size_t)i * 8);
    jd[0] = make_float4(LOG2E*s0, LOG2E*s1, LOG2E*s2, LOG2E*s3);
    jd[1] = make_float4(K * sn,
                        __builtin_amdgcn_exp2f(log_weights[i] * LOG2E),
                        __builtin_amdgcn_exp2f(weights[i] * LOG2E),
                        0.f);

    const float2* p2 = reinterpret_cast<const float2*>(particles) + (size_t)i * 3;
    float2 x01 = p2[0], x23 = p2[1], u01 = p2[2];
    float x[4] = {x01.x, x01.y, x23.x, x23.y};
    float u[2] = {u01.x, u01.y};
#pragma unroll
    for (int k = 0; k < 4; ++k) {
        float mean =       A[k*4+0] * x[0];
        mean = fmaf(A[k*4+1], x[1], mean);
        mean = fmaf(A[k*4+2], x[2], mean);
        mean = fmaf(A[k*4+3], x[3], mean);
        mean = fmaf(B[k*2+0], u[0], mean);
        mean = fmaf(B[k*2+1], u[1], mean);
        msoa[(size_t)k * P + i] = mean * inv_s[k];
    }
}

// ---------------- fused pair + in-block reduce -----------------------------
// grid = P/TR blocks. Block handles rows rowBase..rowBase+TR-1 (uniform
// SGPR means); thread t sweeps j = t, t+BLOCK, ... (P/BLOCK iters).
template <int TR, int BLOCK>
__global__ __launch_bounds__(BLOCK, 4) void pair_fused(
    const float* __restrict__ jdata,   // [P][8]
    const float* __restrict__ msoa,    // [4][P]
    float* __restrict__ out, int P)
{
    constexpr int NW = BLOCK / 64;

    const int tid  = threadIdx.x;
    const int lane = tid & 63;
    const int wv   = tid >> 6;
    const int rowBase = blockIdx.x * TR;

    // block-uniform row means -> scalar loads / SGPRs
    float m0[TR], m1[TR], m2[TR], m3[TR], a1[TR], a2[TR];
#pragma unroll
    for (int r = 0; r < TR; ++r) {
        m0[r] = msoa[0 * (size_t)P + rowBase + r];
        m1[r] = msoa[1 * (size_t)P + rowBase + r];
        m2[r] = msoa[2 * (size_t)P + rowBase + r];
        m3[r] = msoa[3 * (size_t)P + rowBase + r];
        a1[r] = 0.f;
        a2[r] = 0.f;
    }

    // per-lane coalesced j-walk: 2 x dwordx4 per j from L1/L2
    const float4* jf = reinterpret_cast<const float4*>(jdata);
    const int iters = P / BLOCK;     // 32 at P=8192
#pragma unroll 4
    for (int it = 0; it < iters; ++it) {
        const int j = it * BLOCK + tid;
        float4 av = jf[2 * j];
        float4 bv = jf[2 * j + 1];
#pragma unroll
        for (int r = 0; r < TR; ++r) {
            float t = fmaf(m0[r], av.x, bv.x);
            t = fmaf(m1[r], av.y, t);
            t = fmaf(m2[r], av.z, t);
            t = fmaf(m3[r], av.w, t);
            float e = __builtin_amdgcn_exp2f(t);
            a1[r] = fmaf(e, bv.y, a1[r]);
            a2[r] = fmaf(e, bv.z, a2[r]);
        }
    }

    // ---- 64-lane butterfly per row (fixed order -> deterministic) ----
#pragma unroll
    for (int r = 0; r < TR; ++r) {
#pragma unroll
        for (int mask = 32; mask >= 1; mask >>= 1) {
            a1[r] += __shfl_xor(a1[r], mask, 64);
            a2[r] += __shfl_xor(a2[r], mask, 64);
        }
    }

    // ---- cross-wave combine via small LDS, fixed order ----
    __shared__ float red[NW][2 * TR];
    if (lane == 0) {
#pragma unroll
        for (int r = 0; r < TR; ++r) {
            red[wv][r]      = a1[r];
            red[wv][TR + r] = a2[r];
        }
    }
    __syncthreads();
    if (tid < TR) {
        float s1 = 0.f, s2 = 0.f;
#pragma unroll
        for (int w = 0; w < NW; ++w) {
            s1 += red[w][tid];
            s2 += red[w][TR + tid];
        }
        out[rowBase + tid] =
            (__builtin_amdgcn_logf(s2) - __builtin_amdgcn_logf(s1)) * LN2;
    }
}

extern "C" void kernel_launch(void* const* d_in, const int* in_sizes, int n_in,
                              void* d_out, int out_size, void* d_ws, size_t ws_size,
                              hipStream_t stream)
{
    const float* particles   = (const float*)d_in[0];
    const float* samples     = (const float*)d_in[1];
    const float* weights     = (const float*)d_in[2];
    const float* log_weights = (const float*)d_in[3];
    const float* A           = (const float*)d_in[4];
    const float* B           = (const float*)d_in[5];
    const float* log_sigma   = (const float*)d_in[6];

    const int P = in_sizes[2];  // weights is (P,)

    // ws layout: jdata P*8 | msoa 4*P   (393 KB at P=8192)
    float* jdata = (float*)d_ws;
    float* msoa  = jdata + (size_t)P * 8;

    constexpr int BLOCK = 256, TR = 8;

    precompute_k<<<(P + BLOCK - 1) / BLOCK, BLOCK, 0, stream>>>(
        particles, samples, weights, log_weights, A, B, log_sigma,
        jdata, msoa, P);

    pair_fused<TR, BLOCK><<<P / TR, BLOCK, 0, stream>>>(
        jdata, msoa, (float*)d_out, P);
}